// Round 6
// baseline (90.359 us; speedup 1.0000x reference)
//
#include <hip/hip_runtime.h>
#include <math.h>

// ImprovedSpeMamba: b*c*h = 32768 rows; each row = W=128 floats = 4 tokens x 32
#define NROWS 32768
#define NTILES 8192        // 4 rows per wave-tile
#define THREADS 256
#define WPB 4

typedef __attribute__((ext_vector_type(8))) __bf16 bf16x8;
typedef __attribute__((ext_vector_type(4))) float f32x4;

__device__ __forceinline__ float silu_f(float v) {
    return v * __builtin_amdgcn_rcpf(1.f + __expf(-v));
}

// ---------------------------------------------------------------------------
// K1: fused mamba. Wave = 4 rows (M=16 tokens). GEMMs via mfma 16x16x32 bf16.
// xc / silu(z) staged in LDS as bf16. LDS = 35840 B -> 4 blocks/CU.
// NOTE: __launch_bounds__(256) WITHOUT min-waves — the (256,4) hint made the
// allocator pick 64 VGPRs and spill ~2KB/wave/tile to scratch (R5: WRITE_SIZE
// doubled). Compiler's natural ~84-100 VGPR is under the 128 needed for
// 4 waves/SIMD, so occupancy is LDS-bound either way.
// ---------------------------------------------------------------------------
__global__ __launch_bounds__(256) void k_mamba(
    const float* __restrict__ x,
    const float* __restrict__ in_proj_w,   // (128,32)
    const float* __restrict__ conv_w,      // (64,4)
    const float* __restrict__ conv_b,      // (64)
    const float* __restrict__ x_proj_w,    // (34,64)
    const float* __restrict__ dt_proj_w,   // (64,2)
    const float* __restrict__ dt_proj_b,   // (64)
    const float* __restrict__ A_log,       // (64,16)
    const float* __restrict__ Dvec,        // (64)
    const float* __restrict__ out_proj_w,  // (32,64)
    float* __restrict__ xr,                // d_out as xr scratch
    float* __restrict__ S1, float* __restrict__ S2)
{
    __shared__ __align__(16) __bf16 b1f[8*64*8];          // 8 KiB B1 frags
    __shared__ __align__(16) __bf16 xcb[WPB][16*72];      // xc, later y (bf16)
    __shared__ __align__(16) __bf16 szb[WPB][16*72];      // silu(z) (bf16)
    __shared__ __align__(16) float  dbb[WPB][16*36];      // dbl rows (f32)

    const int tid  = threadIdx.x;
    const int wid  = tid >> 6;
    const int lane = tid & 63;
    const int c = lane & 15;      // A-row / B-col / D-col within 16-tile
    const int q = lane >> 4;      // K-octet selector / D-row group

    // ---- stage B1 frags (bf16): lane: col j=c, k=8q+i
    for (int idx = tid; idx < 512; idx += THREADS) {
        int jt = idx >> 6, l = idx & 63, cc = l & 15, qq = l >> 4;
        const float* src = in_proj_w + (jt*16 + cc)*32 + qq*8;
        bf16x8 v;
        #pragma unroll
        for (int i = 0; i < 8; ++i) v[i] = (__bf16)src[i];
        *((bf16x8*)(b1f) + idx) = v;
    }

    // ---- B2 (x_proj) frags in regs: col r = rt*16+c, k = ks*32+8q+i
    bf16x8 B2f[2][3];
    #pragma unroll
    for (int ks = 0; ks < 2; ++ks)
        #pragma unroll
        for (int rt = 0; rt < 3; ++rt) {
            int row = rt*16 + c;
            #pragma unroll
            for (int i = 0; i < 8; ++i)
                B2f[ks][rt][i] = (row < 34) ? (__bf16)x_proj_w[row*64 + ks*32 + q*8 + i]
                                            : (__bf16)0.f;
        }
    // ---- B3 (out_proj) frags
    bf16x8 B3f[2][2];   // [jt][ks]
    #pragma unroll
    for (int jt = 0; jt < 2; ++jt)
        #pragma unroll
        for (int ks = 0; ks < 2; ++ks) {
            int row = jt*16 + c;
            #pragma unroll
            for (int i = 0; i < 8; ++i)
                B3f[jt][ks][i] = (__bf16)out_proj_w[row*64 + ks*32 + q*8 + i];
        }

    // ---- per-lane params
    float cwj[4][4], cbj[4];
    #pragma unroll
    for (int jt = 0; jt < 4; ++jt) {
        int d = jt*16 + c;
        #pragma unroll
        for (int k = 0; k < 4; ++k) cwj[jt][k] = conv_w[d*4 + k];
        cbj[jt] = conv_b[d];
    }
    const float dtw0 = dt_proj_w[lane*2+0], dtw1 = dt_proj_w[lane*2+1];
    const float dtb  = dt_proj_b[lane];
    const float Dd   = Dvec[lane];

    // ---- fast-A check: A_log == log(1..16) (wave-uniform)
    bool okl = true;
    #pragma unroll
    for (int s = 0; s < 16; ++s) {
        float a = __expf(A_log[lane*16 + s]);
        okl = okl && (fabsf(a - (float)(s+1)) < 1e-3f * (float)(s+1));
    }
    const bool fastA = (__ballot(okl) == ~0ull);

    __syncthreads();

    __bf16* xc_ = xcb[wid];
    __bf16* sz_ = szb[wid];
    float*  db_ = dbb[wid];
    const bf16x8* B1p = (const bf16x8*)b1f;
    const int nwaves = gridDim.x * WPB;

    for (int tile = blockIdx.x*WPB + wid; tile < NTILES; tile += nwaves) {
        const int n0 = tile * 4;                 // 4 rows, same (b,c) plane
        const float* xrow = x + n0*128;

        // ---- A1 frag from global (x row-contiguous), f32 -> bf16
        bf16x8 A1;
        {
            const float4* xp4 = (const float4*)(xrow + c*32 + q*8);
            float4 a = xp4[0], b = xp4[1];
            A1[0]=(__bf16)a.x; A1[1]=(__bf16)a.y; A1[2]=(__bf16)a.z; A1[3]=(__bf16)a.w;
            A1[4]=(__bf16)b.x; A1[5]=(__bf16)b.y; A1[6]=(__bf16)b.z; A1[7]=(__bf16)b.w;
        }

        // ---- GEMM1 (8 jt) + conv/silu in D-layout (reg = token)
        #pragma unroll
        for (int jt = 0; jt < 8; ++jt) {
            f32x4 acc = {0.f, 0.f, 0.f, 0.f};
            acc = __builtin_amdgcn_mfma_f32_16x16x32_bf16(A1, B1p[jt*64 + lane], acc, 0, 0, 0);
            if (jt < 4) {
                const float* cw = cwj[jt];
                float cb = cbj[jt];
                float xc0 = cb + cw[3]*acc[0];
                float xc1 = cb + cw[2]*acc[0] + cw[3]*acc[1];
                float xc2 = cb + cw[1]*acc[0] + cw[2]*acc[1] + cw[3]*acc[2];
                float xc3 = cb + cw[0]*acc[0] + cw[1]*acc[1] + cw[2]*acc[2] + cw[3]*acc[3];
                int dcol = jt*16 + c;
                xc_[(4*q+0)*72 + dcol] = (__bf16)silu_f(xc0);
                xc_[(4*q+1)*72 + dcol] = (__bf16)silu_f(xc1);
                xc_[(4*q+2)*72 + dcol] = (__bf16)silu_f(xc2);
                xc_[(4*q+3)*72 + dcol] = (__bf16)silu_f(xc3);
            } else {
                int dcol = (jt-4)*16 + c;
                #pragma unroll
                for (int t = 0; t < 4; ++t)
                    sz_[(4*q+t)*72 + dcol] = (__bf16)silu_f(acc[t]);
            }
        }

        // ---- A2 frags: direct bf16x8 loads from xc
        bf16x8 A2[2];
        #pragma unroll
        for (int ks = 0; ks < 2; ++ks)
            A2[ks] = *(const bf16x8*)&xc_[c*72 + ks*32 + q*8];

        // ---- GEMM2: dbl[m][r]
        f32x4 dacc[3] = {{0,0,0,0},{0,0,0,0},{0,0,0,0}};
        #pragma unroll
        for (int ks = 0; ks < 2; ++ks) {
            dacc[0] = __builtin_amdgcn_mfma_f32_16x16x32_bf16(A2[ks], B2f[ks][0], dacc[0], 0,0,0);
            dacc[1] = __builtin_amdgcn_mfma_f32_16x16x32_bf16(A2[ks], B2f[ks][1], dacc[1], 0,0,0);
            dacc[2] = __builtin_amdgcn_mfma_f32_16x16x32_bf16(A2[ks], B2f[ks][2], dacc[2], 0,0,0);
        }
        // stage dbl: db_[m*36 + 2 + r], r = rt*16+c.
        // GUARD r < 34 EXACTLY (c<2 at rt==2): with stride 36, r=34,35 would
        // spill into the next row / past the buffer (R4's OOB bug).
        #pragma unroll
        for (int rt = 0; rt < 3; ++rt) {
            if (rt < 2 || c < 2) {
                #pragma unroll
                for (int t = 0; t < 4; ++t)
                    db_[(4*q+t)*36 + 2 + rt*16 + c] = dacc[rt][t];
            }
        }

        // ---- selective scan, lane = d, rows sequential
        #pragma unroll
        for (int r = 0; r < 4; ++r) {
            float h[16];
            #pragma unroll
            for (int s = 0; s < 16; ++s) h[s] = 0.f;
            #pragma unroll
            for (int t = 0; t < 4; ++t) {
                const int m = 4*r + t;
                float2 dtv = *(const float2*)&db_[m*36 + 2];
                float p  = fmaf(dtv.y, dtw1, fmaf(dtv.x, dtw0, dtb));
                float ex = __expf(p);
                float t1 = 1.f + ex;
                float e1 = __builtin_amdgcn_rcpf(t1);       // exp(-softplus(p)) exactly
                float delta = (p > 15.f) ? p : __logf(t1);  // softplus(p)
                float u  = (float)xc_[m*72 + lane];
                float sz = (float)sz_[m*72 + lane];
                const float bu = delta * u;

                float dA[16];
                if (fastA) {
                    float e2 = e1*e1, e4 = e2*e2, e8 = e4*e4;
                    dA[0]=e1;      dA[1]=e2;      dA[2]=e2*e1;    dA[3]=e4;
                    dA[4]=e4*e1;   dA[5]=e4*e2;   dA[6]=e4*dA[2]; dA[7]=e8;
                    dA[8]=e8*e1;   dA[9]=e8*e2;   dA[10]=e8*dA[2];dA[11]=e8*e4;
                    dA[12]=e8*dA[4];dA[13]=e8*dA[5];dA[14]=e8*dA[6];dA[15]=e8*e8;
                } else {
                    #pragma unroll
                    for (int s = 0; s < 16; ++s)
                        dA[s] = __expf(-delta * __expf(A_log[lane*16 + s]));
                }

                const float4* B4 = (const float4*)&db_[m*36 + 4];
                const float4* C4 = (const float4*)&db_[m*36 + 20];
                float acc = 0.f;
                #pragma unroll
                for (int s2 = 0; s2 < 4; ++s2) {
                    float4 Bv = B4[s2], Cv = C4[s2];
                    int s = s2*4;
                    h[s+0] = dA[s+0]*h[s+0] + bu*Bv.x;  acc += h[s+0]*Cv.x;
                    h[s+1] = dA[s+1]*h[s+1] + bu*Bv.y;  acc += h[s+1]*Cv.y;
                    h[s+2] = dA[s+2]*h[s+2] + bu*Bv.z;  acc += h[s+2]*Cv.z;
                    h[s+3] = dA[s+3]*h[s+3] + bu*Bv.w;  acc += h[s+3]*Cv.w;
                }
                float y = (acc + u*Dd) * sz;
                xc_[m*72 + lane] = (__bf16)y;    // overlay xc with gated y
            }
        }

        // ---- A3 frags from y (direct bf16x8) + GEMM3 + store + stats
        bf16x8 A3[2];
        #pragma unroll
        for (int ks = 0; ks < 2; ++ks)
            A3[ks] = *(const bf16x8*)&xc_[c*72 + ks*32 + q*8];

        float s1 = 0.f, s2 = 0.f;
        float* orow = xr + n0*128;
        #pragma unroll
        for (int jt = 0; jt < 2; ++jt) {
            f32x4 oacc = {0.f, 0.f, 0.f, 0.f};
            oacc = __builtin_amdgcn_mfma_f32_16x16x32_bf16(A3[0], B3f[jt][0], oacc, 0,0,0);
            oacc = __builtin_amdgcn_mfma_f32_16x16x32_bf16(A3[1], B3f[jt][1], oacc, 0,0,0);
            #pragma unroll
            for (int t = 0; t < 4; ++t) {
                orow[(4*q+t)*32 + jt*16 + c] = oacc[t];
                s1 += oacc[t];
                s2 += oacc[t]*oacc[t];
            }
        }
        #pragma unroll
        for (int off = 32; off > 0; off >>= 1) {
            s1 += __shfl_xor(s1, off, 64);
            s2 += __shfl_xor(s2, off, 64);
        }
        if (lane == 0) {
            atomicAdd(&S1[tile >> 5], s1);
            atomicAdd(&S2[tile >> 5], s2);
        }
    }
}

// ---------------------------------------------------------------------------
// K2: fused SE+GN prologue (per block, redundant but tiny) + elementwise
// out = silu(alpha*xr + beta) + x   (in-place on d_out)
// ---------------------------------------------------------------------------
__global__ __launch_bounds__(256) void k_final(
    const float* __restrict__ x, float* __restrict__ o,
    const float* __restrict__ S1, const float* __restrict__ S2,
    const float* __restrict__ se1_w,  // (32,128)
    const float* __restrict__ se2_w,  // (128,32)
    const float* __restrict__ gn_w, const float* __restrict__ gn_b)
{
    __shared__ float sp[256], sh[64], sg[256], st1[256], st2[256];
    __shared__ float smu[8], sinv[8];
    __shared__ float al[256], be[256];
    const int tid = threadIdx.x;

    sp[tid] = S1[tid] * (1.f/16384.f);
    __syncthreads();

    if (tid < 64) {
        int b = tid >> 5, j = tid & 31;
        float acc = 0.f;
        for (int cc = 0; cc < 128; ++cc) acc += sp[b*128 + cc] * se1_w[j*128 + cc];
        sh[tid] = silu_f(acc);
    }
    __syncthreads();

    {
        int b = tid >> 7, cc = tid & 127;
        float acc = 0.f;
        #pragma unroll
        for (int j = 0; j < 32; ++j) acc += sh[b*32 + j] * se2_w[cc*32 + j];
        float g = __builtin_amdgcn_rcpf(1.f + __expf(-acc));
        sg[tid]  = g;
        st1[tid] = g * S1[tid];
        st2[tid] = g * g * S2[tid];
    }
    __syncthreads();

    if (tid < 8) {
        int b = tid >> 2, gr = tid & 3;
        float m = 0.f, qq = 0.f;
        for (int cc = 0; cc < 32; ++cc) {
            m  += st1[b*128 + gr*32 + cc];
            qq += st2[b*128 + gr*32 + cc];
        }
        const float inv_cnt = 1.f / (32.f * 16384.f);
        m *= inv_cnt; qq *= inv_cnt;
        smu[tid]  = m;
        sinv[tid] = rsqrtf(qq - m*m + 1e-5f);
    }
    __syncthreads();

    {
        int b = tid >> 7, cc = tid & 127;
        int gi = b*4 + (cc >> 5);
        float iv = sinv[gi], mu = smu[gi], g = sg[tid], w = gn_w[cc];
        al[tid] = g * iv * w;
        be[tid] = gn_b[cc] - mu * iv * w;
    }
    __syncthreads();

    const int total4 = (2*128*128*128) / 4;
    const float4* x4 = (const float4*)x;
    float4* o4 = (float4*)o;
    for (int i = blockIdx.x*blockDim.x + tid; i < total4;
         i += gridDim.x*blockDim.x) {
        int bc = i >> 12;
        float a = al[bc], b = be[bc];
        float4 v = o4[i], xv = x4[i];
        float u;
        u = a*v.x + b;  v.x = silu_f(u) + xv.x;
        u = a*v.y + b;  v.y = silu_f(u) + xv.y;
        u = a*v.z + b;  v.z = silu_f(u) + xv.z;
        u = a*v.w + b;  v.w = silu_f(u) + xv.w;
        o4[i] = v;
    }
}

extern "C" void kernel_launch(void* const* d_in, const int* in_sizes, int n_in,
                              void* d_out, int out_size, void* d_ws, size_t ws_size,
                              hipStream_t stream) {
    const float* x          = (const float*)d_in[0];
    const float* in_proj_w  = (const float*)d_in[1];
    const float* conv_w     = (const float*)d_in[2];
    const float* conv_b     = (const float*)d_in[3];
    const float* x_proj_w   = (const float*)d_in[4];
    const float* dt_proj_w  = (const float*)d_in[5];
    const float* dt_proj_b  = (const float*)d_in[6];
    const float* A_log      = (const float*)d_in[7];
    const float* Dvec       = (const float*)d_in[8];
    const float* out_proj_w = (const float*)d_in[9];
    const float* se1_w      = (const float*)d_in[10];
    const float* se2_w      = (const float*)d_in[11];
    const float* gn_w       = (const float*)d_in[12];
    const float* gn_b       = (const float*)d_in[13];

    float* out = (float*)d_out;
    float* ws  = (float*)d_ws;
    float* S1 = ws;           // 256
    float* S2 = ws + 256;     // 256

    hipMemsetAsync(ws, 0, 512*sizeof(float), stream);
    k_mamba<<<1024, THREADS, 0, stream>>>(x, in_proj_w, conv_w, conv_b, x_proj_w,
                                          dt_proj_w, dt_proj_b, A_log, Dvec,
                                          out_proj_w, out, S1, S2);
    k_final<<<2048, THREADS, 0, stream>>>(x, out, S1, S2, se1_w, se2_w, gn_w, gn_b);
}

// Round 7
// 88.485 us; speedup vs baseline: 1.0212x; 1.0212x over previous
//
#include <hip/hip_runtime.h>
#include <math.h>

// ImprovedSpeMamba: b*c*h = 32768 rows; each row = W=128 floats = 4 tokens x 32
#define NROWS 32768
#define NTILES 8192        // 4 rows per wave-tile
#define THREADS 256
#define WPB 4

typedef __attribute__((ext_vector_type(8))) __bf16 bf16x8;
typedef __attribute__((ext_vector_type(4))) float f32x4;
typedef __attribute__((ext_vector_type(2))) float f32x2;

__device__ __forceinline__ float silu_f(float v) {
    return v * __builtin_amdgcn_rcpf(1.f + __expf(-v));
}
// CDNA packed-f32 (VOP3P): 2 f32 lanes per issue slot, full rate.
__device__ __forceinline__ f32x2 pk_fma(f32x2 a, f32x2 b, f32x2 c) {
    f32x2 d;
    asm("v_pk_fma_f32 %0, %1, %2, %3" : "=v"(d) : "v"(a), "v"(b), "v"(c));
    return d;
}
__device__ __forceinline__ f32x2 pk_mul(f32x2 a, f32x2 b) {
    f32x2 d;
    asm("v_pk_mul_f32 %0, %1, %2" : "=v"(d) : "v"(a), "v"(b));
    return d;
}

// ---------------------------------------------------------------------------
// K1: fused mamba. Wave = 4 rows (M=16 tokens). GEMMs via mfma 16x16x32 bf16.
// xc / silu(z) staged in LDS as bf16. LDS = 35840 B -> 4 blocks/CU.
// Scan uses v_pk_fma_f32 pairs (R7): h/B/C/dA as f32x2, halves scan VALU issue.
// NO min-waves launch bound (R5: it forced 64 VGPR + scratch spills).
// ---------------------------------------------------------------------------
__global__ __launch_bounds__(256) void k_mamba(
    const float* __restrict__ x,
    const float* __restrict__ in_proj_w,   // (128,32)
    const float* __restrict__ conv_w,      // (64,4)
    const float* __restrict__ conv_b,      // (64)
    const float* __restrict__ x_proj_w,    // (34,64)
    const float* __restrict__ dt_proj_w,   // (64,2)
    const float* __restrict__ dt_proj_b,   // (64)
    const float* __restrict__ A_log,       // (64,16)
    const float* __restrict__ Dvec,        // (64)
    const float* __restrict__ out_proj_w,  // (32,64)
    float* __restrict__ xr,                // d_out as xr scratch
    float* __restrict__ S1, float* __restrict__ S2)
{
    __shared__ __align__(16) __bf16 b1f[8*64*8];          // 8 KiB B1 frags
    __shared__ __align__(16) __bf16 xcb[WPB][16*72];      // xc, later y (bf16)
    __shared__ __align__(16) __bf16 szb[WPB][16*72];      // silu(z) (bf16)
    __shared__ __align__(16) float  dbb[WPB][16*36];      // dbl rows (f32)

    const int tid  = threadIdx.x;
    const int wid  = tid >> 6;
    const int lane = tid & 63;
    const int c = lane & 15;      // A-row / B-col / D-col within 16-tile
    const int q = lane >> 4;      // K-octet selector / D-row group

    // ---- stage B1 frags (bf16): lane: col j=c, k=8q+i
    for (int idx = tid; idx < 512; idx += THREADS) {
        int jt = idx >> 6, l = idx & 63, cc = l & 15, qq = l >> 4;
        const float* src = in_proj_w + (jt*16 + cc)*32 + qq*8;
        bf16x8 v;
        #pragma unroll
        for (int i = 0; i < 8; ++i) v[i] = (__bf16)src[i];
        *((bf16x8*)(b1f) + idx) = v;
    }

    // ---- B2 (x_proj) frags in regs: col r = rt*16+c, k = ks*32+8q+i
    bf16x8 B2f[2][3];
    #pragma unroll
    for (int ks = 0; ks < 2; ++ks)
        #pragma unroll
        for (int rt = 0; rt < 3; ++rt) {
            int row = rt*16 + c;
            #pragma unroll
            for (int i = 0; i < 8; ++i)
                B2f[ks][rt][i] = (row < 34) ? (__bf16)x_proj_w[row*64 + ks*32 + q*8 + i]
                                            : (__bf16)0.f;
        }
    // ---- B3 (out_proj) frags
    bf16x8 B3f[2][2];   // [jt][ks]
    #pragma unroll
    for (int jt = 0; jt < 2; ++jt)
        #pragma unroll
        for (int ks = 0; ks < 2; ++ks) {
            int row = jt*16 + c;
            #pragma unroll
            for (int i = 0; i < 8; ++i)
                B3f[jt][ks][i] = (__bf16)out_proj_w[row*64 + ks*32 + q*8 + i];
        }

    // ---- per-lane params
    float cwj[4][4], cbj[4];
    #pragma unroll
    for (int jt = 0; jt < 4; ++jt) {
        int d = jt*16 + c;
        #pragma unroll
        for (int k = 0; k < 4; ++k) cwj[jt][k] = conv_w[d*4 + k];
        cbj[jt] = conv_b[d];
    }
    const float dtw0 = dt_proj_w[lane*2+0], dtw1 = dt_proj_w[lane*2+1];
    const float dtb  = dt_proj_b[lane];
    const float Dd   = Dvec[lane];

    // ---- fast-A check: A_log == log(1..16) (wave-uniform)
    bool okl = true;
    #pragma unroll
    for (int s = 0; s < 16; ++s) {
        float a = __expf(A_log[lane*16 + s]);
        okl = okl && (fabsf(a - (float)(s+1)) < 1e-3f * (float)(s+1));
    }
    const bool fastA = (__ballot(okl) == ~0ull);

    __syncthreads();

    __bf16* xc_ = xcb[wid];
    __bf16* sz_ = szb[wid];
    float*  db_ = dbb[wid];
    const bf16x8* B1p = (const bf16x8*)b1f;
    const int nwaves = gridDim.x * WPB;

    for (int tile = blockIdx.x*WPB + wid; tile < NTILES; tile += nwaves) {
        const int n0 = tile * 4;                 // 4 rows, same (b,c) plane
        const float* xrow = x + n0*128;

        // ---- A1 frag from global (x row-contiguous), f32 -> bf16
        bf16x8 A1;
        {
            const float4* xp4 = (const float4*)(xrow + c*32 + q*8);
            float4 a = xp4[0], b = xp4[1];
            A1[0]=(__bf16)a.x; A1[1]=(__bf16)a.y; A1[2]=(__bf16)a.z; A1[3]=(__bf16)a.w;
            A1[4]=(__bf16)b.x; A1[5]=(__bf16)b.y; A1[6]=(__bf16)b.z; A1[7]=(__bf16)b.w;
        }

        // ---- GEMM1 (8 jt) + conv/silu in D-layout (reg = token)
        #pragma unroll
        for (int jt = 0; jt < 8; ++jt) {
            f32x4 acc = {0.f, 0.f, 0.f, 0.f};
            acc = __builtin_amdgcn_mfma_f32_16x16x32_bf16(A1, B1p[jt*64 + lane], acc, 0, 0, 0);
            if (jt < 4) {
                const float* cw = cwj[jt];
                float cb = cbj[jt];
                float xc0 = cb + cw[3]*acc[0];
                float xc1 = cb + cw[2]*acc[0] + cw[3]*acc[1];
                float xc2 = cb + cw[1]*acc[0] + cw[2]*acc[1] + cw[3]*acc[2];
                float xc3 = cb + cw[0]*acc[0] + cw[1]*acc[1] + cw[2]*acc[2] + cw[3]*acc[3];
                int dcol = jt*16 + c;
                xc_[(4*q+0)*72 + dcol] = (__bf16)silu_f(xc0);
                xc_[(4*q+1)*72 + dcol] = (__bf16)silu_f(xc1);
                xc_[(4*q+2)*72 + dcol] = (__bf16)silu_f(xc2);
                xc_[(4*q+3)*72 + dcol] = (__bf16)silu_f(xc3);
            } else {
                int dcol = (jt-4)*16 + c;
                #pragma unroll
                for (int t = 0; t < 4; ++t)
                    sz_[(4*q+t)*72 + dcol] = (__bf16)silu_f(acc[t]);
            }
        }

        // ---- A2 frags: direct bf16x8 loads from xc
        bf16x8 A2[2];
        #pragma unroll
        for (int ks = 0; ks < 2; ++ks)
            A2[ks] = *(const bf16x8*)&xc_[c*72 + ks*32 + q*8];

        // ---- GEMM2: dbl[m][r]
        f32x4 dacc[3] = {{0,0,0,0},{0,0,0,0},{0,0,0,0}};
        #pragma unroll
        for (int ks = 0; ks < 2; ++ks) {
            dacc[0] = __builtin_amdgcn_mfma_f32_16x16x32_bf16(A2[ks], B2f[ks][0], dacc[0], 0,0,0);
            dacc[1] = __builtin_amdgcn_mfma_f32_16x16x32_bf16(A2[ks], B2f[ks][1], dacc[1], 0,0,0);
            dacc[2] = __builtin_amdgcn_mfma_f32_16x16x32_bf16(A2[ks], B2f[ks][2], dacc[2], 0,0,0);
        }
        // stage dbl: db_[m*36 + 2 + r], r = rt*16+c.
        // GUARD r < 34 EXACTLY (c<2 at rt==2): stride-36 rows spill otherwise.
        #pragma unroll
        for (int rt = 0; rt < 3; ++rt) {
            if (rt < 2 || c < 2) {
                #pragma unroll
                for (int t = 0; t < 4; ++t)
                    db_[(4*q+t)*36 + 2 + rt*16 + c] = dacc[rt][t];
            }
        }

        // ---- selective scan, lane = d, rows sequential; pk-f32 pairs
        #pragma unroll
        for (int r = 0; r < 4; ++r) {
            f32x2 h2[8];
            #pragma unroll
            for (int s = 0; s < 8; ++s) h2[s] = (f32x2){0.f, 0.f};
            #pragma unroll
            for (int t = 0; t < 4; ++t) {
                const int m = 4*r + t;
                float2 dtv = *(const float2*)&db_[m*36 + 2];
                float p  = fmaf(dtv.y, dtw1, fmaf(dtv.x, dtw0, dtb));
                float ex = __expf(p);
                float t1 = 1.f + ex;
                float e1 = __builtin_amdgcn_rcpf(t1);       // exp(-softplus(p)) exactly
                float delta = (p > 15.f) ? p : __logf(t1);  // softplus(p)
                float u  = (float)xc_[m*72 + lane];
                float sz = (float)sz_[m*72 + lane];
                const float bu = delta * u;
                const f32x2 bu2 = {bu, bu};

                // dA pairs: {e^1,e^2}, {e^3,e^4}, ... via pk_mul chain by {e^2,e^2}
                f32x2 dA2[8];
                if (fastA) {
                    float e2 = e1 * e1;
                    dA2[0][0] = e1; dA2[0][1] = e2;
                    f32x2 ee = {e2, e2};
                    #pragma unroll
                    for (int i = 1; i < 8; ++i) dA2[i] = pk_mul(dA2[i-1], ee);
                } else {
                    #pragma unroll
                    for (int s = 0; s < 16; ++s)
                        dA2[s>>1][s&1] = __expf(-delta * __expf(A_log[lane*16 + s]));
                }

                const f32x2* B2v = (const f32x2*)&db_[m*36 + 4];
                const f32x2* C2v = (const f32x2*)&db_[m*36 + 20];
                f32x2 accA = {0.f, 0.f}, accB = {0.f, 0.f};
                #pragma unroll
                for (int i = 0; i < 8; ++i) {
                    h2[i] = pk_fma(dA2[i], h2[i], pk_mul(bu2, B2v[i]));
                    if (i & 1) accB = pk_fma(h2[i], C2v[i], accB);
                    else       accA = pk_fma(h2[i], C2v[i], accA);
                }
                float acc = (accA[0] + accA[1]) + (accB[0] + accB[1]);
                float y = fmaf(u, Dd, acc) * sz;
                xc_[m*72 + lane] = (__bf16)y;    // overlay xc with gated y
            }
        }

        // ---- A3 frags from y (direct bf16x8) + GEMM3 + store + stats
        bf16x8 A3[2];
        #pragma unroll
        for (int ks = 0; ks < 2; ++ks)
            A3[ks] = *(const bf16x8*)&xc_[c*72 + ks*32 + q*8];

        float s1 = 0.f, s2 = 0.f;
        float* orow = xr + n0*128;
        #pragma unroll
        for (int jt = 0; jt < 2; ++jt) {
            f32x4 oacc = {0.f, 0.f, 0.f, 0.f};
            oacc = __builtin_amdgcn_mfma_f32_16x16x32_bf16(A3[0], B3f[jt][0], oacc, 0,0,0);
            oacc = __builtin_amdgcn_mfma_f32_16x16x32_bf16(A3[1], B3f[jt][1], oacc, 0,0,0);
            #pragma unroll
            for (int t = 0; t < 4; ++t) {
                orow[(4*q+t)*32 + jt*16 + c] = oacc[t];
                s1 += oacc[t];
                s2 += oacc[t]*oacc[t];
            }
        }
        #pragma unroll
        for (int off = 32; off > 0; off >>= 1) {
            s1 += __shfl_xor(s1, off, 64);
            s2 += __shfl_xor(s2, off, 64);
        }
        if (lane == 0) {
            atomicAdd(&S1[tile >> 5], s1);
            atomicAdd(&S2[tile >> 5], s2);
        }
    }
}

// ---------------------------------------------------------------------------
// K2: fused SE+GN prologue (per block, redundant but tiny) + elementwise
// out = silu(alpha*xr + beta) + x   (in-place on d_out)
// ---------------------------------------------------------------------------
__global__ __launch_bounds__(256) void k_final(
    const float* __restrict__ x, float* __restrict__ o,
    const float* __restrict__ S1, const float* __restrict__ S2,
    const float* __restrict__ se1_w,  // (32,128)
    const float* __restrict__ se2_w,  // (128,32)
    const float* __restrict__ gn_w, const float* __restrict__ gn_b)
{
    __shared__ float sp[256], sh[64], sg[256], st1[256], st2[256];
    __shared__ float smu[8], sinv[8];
    __shared__ float al[256], be[256];
    const int tid = threadIdx.x;

    sp[tid] = S1[tid] * (1.f/16384.f);
    __syncthreads();

    if (tid < 64) {
        int b = tid >> 5, j = tid & 31;
        float acc = 0.f;
        for (int cc = 0; cc < 128; ++cc) acc += sp[b*128 + cc] * se1_w[j*128 + cc];
        sh[tid] = silu_f(acc);
    }
    __syncthreads();

    {
        int b = tid >> 7, cc = tid & 127;
        float acc = 0.f;
        #pragma unroll
        for (int j = 0; j < 32; ++j) acc += sh[b*32 + j] * se2_w[cc*32 + j];
        float g = __builtin_amdgcn_rcpf(1.f + __expf(-acc));
        sg[tid]  = g;
        st1[tid] = g * S1[tid];
        st2[tid] = g * g * S2[tid];
    }
    __syncthreads();

    if (tid < 8) {
        int b = tid >> 2, gr = tid & 3;
        float m = 0.f, qq = 0.f;
        for (int cc = 0; cc < 32; ++cc) {
            m  += st1[b*128 + gr*32 + cc];
            qq += st2[b*128 + gr*32 + cc];
        }
        const float inv_cnt = 1.f / (32.f * 16384.f);
        m *= inv_cnt; qq *= inv_cnt;
        smu[tid]  = m;
        sinv[tid] = rsqrtf(qq - m*m + 1e-5f);
    }
    __syncthreads();

    {
        int b = tid >> 7, cc = tid & 127;
        int gi = b*4 + (cc >> 5);
        float iv = sinv[gi], mu = smu[gi], g = sg[tid], w = gn_w[cc];
        al[tid] = g * iv * w;
        be[tid] = gn_b[cc] - mu * iv * w;
    }
    __syncthreads();

    const int total4 = (2*128*128*128) / 4;
    const float4* x4 = (const float4*)x;
    float4* o4 = (float4*)o;
    for (int i = blockIdx.x*blockDim.x + tid; i < total4;
         i += gridDim.x*blockDim.x) {
        int bc = i >> 12;
        float a = al[bc], b = be[bc];
        float4 v = o4[i], xv = x4[i];
        float u;
        u = a*v.x + b;  v.x = silu_f(u) + xv.x;
        u = a*v.y + b;  v.y = silu_f(u) + xv.y;
        u = a*v.z + b;  v.z = silu_f(u) + xv.z;
        u = a*v.w + b;  v.w = silu_f(u) + xv.w;
        o4[i] = v;
    }
}

extern "C" void kernel_launch(void* const* d_in, const int* in_sizes, int n_in,
                              void* d_out, int out_size, void* d_ws, size_t ws_size,
                              hipStream_t stream) {
    const float* x          = (const float*)d_in[0];
    const float* in_proj_w  = (const float*)d_in[1];
    const float* conv_w     = (const float*)d_in[2];
    const float* conv_b     = (const float*)d_in[3];
    const float* x_proj_w   = (const float*)d_in[4];
    const float* dt_proj_w  = (const float*)d_in[5];
    const float* dt_proj_b  = (const float*)d_in[6];
    const float* A_log      = (const float*)d_in[7];
    const float* Dvec       = (const float*)d_in[8];
    const float* out_proj_w = (const float*)d_in[9];
    const float* se1_w      = (const float*)d_in[10];
    const float* se2_w      = (const float*)d_in[11];
    const float* gn_w       = (const float*)d_in[12];
    const float* gn_b       = (const float*)d_in[13];

    float* out = (float*)d_out;
    float* ws  = (float*)d_ws;
    float* S1 = ws;           // 256
    float* S2 = ws + 256;     // 256

    hipMemsetAsync(ws, 0, 512*sizeof(float), stream);
    k_mamba<<<1024, THREADS, 0, stream>>>(x, in_proj_w, conv_w, conv_b, x_proj_w,
                                          dt_proj_w, dt_proj_b, A_log, Dvec,
                                          out_proj_w, out, S1, S2);
    k_final<<<2048, THREADS, 0, stream>>>(x, out, S1, S2, se1_w, se2_w, gn_w, gn_b);
}